// Round 7
// baseline (250.331 us; speedup 1.0000x reference)
//
#include <hip/hip_runtime.h>
#include <hip/hip_bf16.h>

#define NN 100000
#define NE 1000000
#define NR 8

// binned counting sort params
#define EB 4096
#define NBLK 245          // ceil(NE/EB)
#define NBUCK 196         // dst>>9 buckets
#define NT (NBUCK*NBLK)   // 48020 histogram cells
#define NBB 188           // ceil(NT/256)

typedef unsigned short u16;
typedef unsigned int u32;
typedef __attribute__((ext_vector_type(8))) short bf16x8;
typedef __attribute__((ext_vector_type(4))) float f32x4;

static __device__ __forceinline__ float bf2f(u16 u) {
    union { u32 i; float f; } v; v.i = ((u32)u) << 16; return v.f;
}
static __device__ __forceinline__ u16 f2bf(float f) {
    __hip_bfloat16 h = __float2bfloat16(f);
    return *reinterpret_cast<u16*>(&h);
}
static __device__ __forceinline__ float ldf(const void* p, int idx, int isf32) {
    return isf32 ? ((const float*)p)[idx] : bf2f(((const u16*)p)[idx]);
}

// --------------------------------------------------------------------------
// dtype detect: bf16 N(0,1) words have sane exponents; fp32 mantissa words don't
// --------------------------------------------------------------------------
__global__ void k_detect(const u16* __restrict__ xw, int* __restrict__ flag)
{
    int t = threadIdx.x;
    int insane = 0;
    for (int k = t; k < 512; k += 64) {
        u16 w = xw[k];
        int ex = (w >> 7) & 0xFF;
        bool sane = ((w & 0x7FFF) == 0) || (ex >= 96 && ex <= 159);
        insane += sane ? 0 : 1;
    }
    for (int off = 32; off; off >>= 1) insane += __shfl_down(insane, off);
    if (t == 0) *flag = (insane > 50) ? 1 : 0;
}

// canonicalize x -> bf16 xb[NN*64]
__global__ void k_cvt(const void* __restrict__ xin, const int* __restrict__ flag,
                      u16* __restrict__ xb)
{
    int i = blockIdx.x * blockDim.x + threadIdx.x;   // 8 elems per thread
    if (i >= NN * 8) return;
    if (*flag) {
        const float* xf = (const float*)xin;
        u16 o[8];
#pragma unroll
        for (int j = 0; j < 8; ++j) o[j] = f2bf(xf[i * 8 + j]);
        uint4 v;
        v.x = (u32)o[0] | ((u32)o[1] << 16);
        v.y = (u32)o[2] | ((u32)o[3] << 16);
        v.z = (u32)o[4] | ((u32)o[5] << 16);
        v.w = (u32)o[6] | ((u32)o[7] << 16);
        ((uint4*)xb)[i] = v;
    } else {
        ((uint4*)xb)[i] = ((const uint4*)xin)[i];
    }
}

// --------------------------------------------------------------------------
// K0: swizzled B operand per relation in MFMA B-frag order
// --------------------------------------------------------------------------
__global__ void k0_prep(const void* __restrict__ cw, const void* __restrict__ al,
                        const void* __restrict__ ar, const int* __restrict__ flag,
                        u16* __restrict__ Bpre)
{
    int tid = blockIdx.x * blockDim.x + threadIdx.x;
    if (tid >= NR * 5120) return;
    int isf32 = *flag;
    int r = tid / 5120, rem = tid % 5120;
    int c = rem >> 3, j = rem & 7;
    int nt = c >> 7, kk = (c >> 6) & 1, lc = c & 63;
    int i = kk * 32 + ((lc >> 4) << 3) + j;
    int d = lc & 15;
    u16 val;
    if (nt < 4) {
        val = f2bf(ldf(cw, ((r * 4 + nt) * 64 + i) * 16 + d, isf32));
    } else if (d < 8) {
        int h = d >> 1;
        const void* attn = (d & 1) ? ar : al;
        float s = 0.f;
        for (int dd = 0; dd < 16; ++dd)
            s += ldf(cw, ((r * 4 + h) * 64 + i) * 16 + dd, isf32)
               * ldf(attn, (r * 4 + h) * 16 + dd, isf32);
        val = f2bf(s);
    } else {
        val = 0;
    }
    Bpre[tid] = val;
}

// --------------------------------------------------------------------------
// K1: feat_all[r][n][0:64] = x[n] @ W[r]  (+ el/er via appended 5th B tile)
// --------------------------------------------------------------------------
__global__ __launch_bounds__(256) void k1_feat(
    const u16* __restrict__ xb, const u16* __restrict__ Bpre,
    u16* __restrict__ feat_all, float* __restrict__ el_all, float* __restrict__ er_all)
{
    __shared__ alignas(16) u16 ldsA[4096];
    __shared__ alignas(16) u16 ldsB[5120];
    int n0 = blockIdx.x * 64;
    int r = blockIdx.y;
    int tid = threadIdx.x;
    int wave = tid >> 6, lane = tid & 63;

    for (int c = tid; c < 512; c += 256) {
        int mt = c >> 7, kk = (c >> 6) & 1, lc = c & 63;
        int node = n0 + mt * 16 + (lc & 15);
        if (node >= NN) node = NN - 1;
        int kbase = kk * 32 + ((lc >> 4) << 3);
        *(uint4*)&ldsA[c * 8] = *(const uint4*)&xb[node * 64 + kbase];
    }
    for (int c = tid; c < 640; c += 256)
        *(uint4*)&ldsB[c * 8] = *(const uint4*)&Bpre[r * 5120 + c * 8];
    __syncthreads();

    bf16x8 afrag0 = *(bf16x8*)&ldsA[((wave * 2 + 0) * 64 + lane) * 8];
    bf16x8 afrag1 = *(bf16x8*)&ldsA[((wave * 2 + 1) * 64 + lane) * 8];
    f32x4 acc[5];
#pragma unroll
    for (int nt = 0; nt < 5; ++nt) acc[nt] = f32x4{0.f, 0.f, 0.f, 0.f};
#pragma unroll
    for (int nt = 0; nt < 5; ++nt) {
        bf16x8 b0 = *(bf16x8*)&ldsB[((nt * 2 + 0) * 64 + lane) * 8];
        bf16x8 b1 = *(bf16x8*)&ldsB[((nt * 2 + 1) * 64 + lane) * 8];
        acc[nt] = __builtin_amdgcn_mfma_f32_16x16x32_bf16(afrag0, b0, acc[nt], 0, 0, 0);
        acc[nt] = __builtin_amdgcn_mfma_f32_16x16x32_bf16(afrag1, b1, acc[nt], 0, 0, 0);
    }

    int col = lane & 15, quad = lane >> 4;
    if (col < 8) {
        int h = col >> 1;
        float* dstp = (col & 1) ? er_all : el_all;
#pragma unroll
        for (int reg = 0; reg < 4; ++reg) {
            int node = n0 + wave * 16 + quad * 4 + reg;
            if (node < NN) dstp[(r * NN + node) * 4 + h] = acc[4][reg];
        }
    }
    __syncthreads();
#pragma unroll
    for (int nt = 0; nt < 4; ++nt) {
        int cg = nt * 16 + col;
#pragma unroll
        for (int reg = 0; reg < 4; ++reg) {
            int row = quad * 4 + reg;
            ldsA[(wave * 16 + row) * 64 + cg] = f2bf(acc[nt][reg]);
        }
    }
    __syncthreads();
    for (int c = tid; c < 512; c += 256) {
        int nl = c >> 3, part = c & 7;
        int node = n0 + nl;
        if (node < NN)
            *(uint4*)&feat_all[(r * NN + node) * 64 + part * 8] = *(uint4*)&ldsA[c * 8];
    }
}

// --------------------------------------------------------------------------
// Binned counting sort by dst — no global atomics, coalesced writes.
// --------------------------------------------------------------------------
__global__ __launch_bounds__(256) void k_binA(const int* __restrict__ dsti,
                                              int* __restrict__ histT)
{
    __shared__ int hist[NBUCK];
    int t = threadIdx.x, blk = blockIdx.x;
    if (t < NBUCK) hist[t] = 0;
    __syncthreads();
    int base = blk * EB;
    for (int j = 0; j < EB; j += 256) {
        int e = base + j + t;
        if (e < NE) atomicAdd(&hist[dsti[e] >> 9], 1);
    }
    __syncthreads();
    if (t < NBUCK) histT[t * NBLK + blk] = hist[t];
}

__global__ __launch_bounds__(256) void k_scanB1(int* __restrict__ histT,
                                                int* __restrict__ bsum)
{
    __shared__ int wtot[4];
    int t = threadIdx.x;
    int gi = blockIdx.x * 256 + t;
    int v = (gi < NT) ? histT[gi] : 0;
    int lane = t & 63, w = t >> 6;
    int s = v;
#pragma unroll
    for (int m = 1; m < 64; m <<= 1) {
        int u = __shfl_up(s, m);
        if (lane >= m) s += u;
    }
    if (lane == 63) wtot[w] = s;
    __syncthreads();
    int wb = 0;
    for (int i = 0; i < w; ++i) wb += wtot[i];
    if (gi < NT) histT[gi] = wb + s - v;
    if (t == 255) bsum[blockIdx.x] = wb + s;
}

__global__ __launch_bounds__(256) void k_scanB2(const int* __restrict__ bsum,
                                                int* __restrict__ boff)
{
    __shared__ int wtot[4];
    int t = threadIdx.x;
    int v = (t < NBB) ? bsum[t] : 0;
    int lane = t & 63, w = t >> 6;
    int s = v;
#pragma unroll
    for (int m = 1; m < 64; m <<= 1) {
        int u = __shfl_up(s, m);
        if (lane >= m) s += u;
    }
    if (lane == 63) wtot[w] = s;
    __syncthreads();
    int wb = 0;
    for (int i = 0; i < w; ++i) wb += wtot[i];
    if (t < NBB) boff[t] = wb + s - v;
}

__global__ __launch_bounds__(256) void k_scanB3(const int* __restrict__ boff,
                                                int* __restrict__ histT,
                                                int* __restrict__ bstart)
{
    int gi = blockIdx.x * 256 + threadIdx.x;
    if (gi < NT) {
        int val = histT[gi] + boff[blockIdx.x];
        histT[gi] = val;
        if (gi % NBLK == 0) bstart[gi / NBLK] = val;
    }
    if (gi == 0) bstart[NBUCK] = NE;
}

// key = (dst&511)<<20 | rel<<17 | src   (29 bits)
__global__ __launch_bounds__(256) void k_binC(
    const int* __restrict__ srci, const int* __restrict__ dsti,
    const int* __restrict__ reli, const int* __restrict__ histT,
    int* __restrict__ key_b)
{
    __shared__ int cur[NBUCK];
    int t = threadIdx.x, blk = blockIdx.x;
    if (t < NBUCK) cur[t] = histT[t * NBLK + blk];
    __syncthreads();
    int base = blk * EB;
    for (int j = 0; j < EB; j += 256) {
        int e = base + j + t;
        if (e < NE) {
            int d = dsti[e];
            int key = ((d & 511) << 20) | (reli[e] << 17) | srci[e];
            int pos = atomicAdd(&cur[d >> 9], 1);
            key_b[pos] = key;
        }
    }
}

__global__ __launch_bounds__(512) void k_binD(
    const int* __restrict__ bstart, const int* __restrict__ key_b,
    int* __restrict__ key_s, int* __restrict__ off)
{
    __shared__ int cnt[512];
    __shared__ int wtot[8];
    int t = threadIdx.x, b = blockIdx.x;
    int s0 = bstart[b], s1 = bstart[b + 1];
    cnt[t] = 0;
    __syncthreads();
    for (int j = s0 + t; j < s1; j += 512)
        atomicAdd(&cnt[(key_b[j] >> 20) & 511], 1);
    __syncthreads();
    int v = cnt[t];
    int lane = t & 63, w = t >> 6;
    int s = v;
#pragma unroll
    for (int m = 1; m < 64; m <<= 1) {
        int u = __shfl_up(s, m);
        if (lane >= m) s += u;
    }
    if (lane == 63) wtot[w] = s;
    __syncthreads();
    int wb = 0;
    for (int i = 0; i < w; ++i) wb += wtot[i];
    int excl = s0 + wb + s - v;
    int d = (b << 9) + t;
    if (d < NN) off[d] = excl;
    __syncthreads();
    cnt[t] = excl;
    if (b == 0 && t == 0) off[NN] = NE;
    __syncthreads();
    for (int j = s0 + t; j < s1; j += 512) {
        int key = key_b[j];
        int pos = atomicAdd(&cnt[(key >> 20) & 511], 1);
        key_s[pos] = key;
    }
}

// --------------------------------------------------------------------------
// K2e: edge-parallel ee = exp(leaky(el+er)) over sorted keys -> ew[e] (16B,
// coalesced). Block b covers bucket b so dst is reconstructible.
// --------------------------------------------------------------------------
__global__ __launch_bounds__(256) void k2e(
    const int* __restrict__ bstart, const int* __restrict__ key_s,
    const float* __restrict__ el_all, const float* __restrict__ er_all,
    f32x4* __restrict__ ew)
{
    int b = blockIdx.x;
    int s0 = bstart[b], s1 = bstart[b + 1];
    for (int j = s0 + threadIdx.x; j < s1; j += 256) {
        int key = key_s[j];
        int rel = (key >> 17) & 7, src = key & 131071;
        int d = (b << 9) | ((key >> 20) & 511);
        f32x4 el = *(const f32x4*)&el_all[(rel * NN + src) * 4];
        f32x4 er = *(const f32x4*)&er_all[(rel * NN + d) * 4];
        f32x4 ee;
#pragma unroll
        for (int q = 0; q < 4; ++q) {
            float v = el[q] + er[q];
            v = v > 0.f ? v : 0.2f * v;
            ee[q] = __expf(v);
        }
        ew[j] = ee;
    }
}

// --------------------------------------------------------------------------
// K3: one wave per dst node, single pass: stage key+ee chunk in LDS,
// accumulate raw Σ ee*feat (8-wide batched gathers), scale by 1/denom at end.
// --------------------------------------------------------------------------
__global__ __launch_bounds__(256) void k3_node(
    const int* __restrict__ off, const int* __restrict__ key_s,
    const f32x4* __restrict__ ew, const u16* __restrict__ feat_all,
    const void* __restrict__ bias, const int* __restrict__ flag,
    void* __restrict__ out)
{
    __shared__ int   ldsK[4][64];
    __shared__ float ldsE[4][64][4];
    int wave = threadIdx.x >> 6, lane = threadIdx.x & 63;
    int h = lane >> 4;
    int gw = blockIdx.x * 4 + wave;
    int nw = gridDim.x * 4;
    int isf32 = *flag;
    float bv = ldf(bias, lane, isf32);

    for (int d = gw; d < NN; d += nw) {
        int start = off[d], end = off[d + 1];
        int deg = end - start;

        float acc = 0.f;
        f32x4 dsum = f32x4{0.f, 0.f, 0.f, 0.f};
        for (int base = 0; base < deg; base += 64) {
            int cn = min(64, deg - base);
            int j = base + lane;
            if (lane < cn) {
                int key = key_s[start + j];
                ldsK[wave][lane] = ((key >> 17) & 7) * NN + (key & 131071);
                f32x4 ee = ew[start + j];
                *(f32x4*)&ldsE[wave][lane][0] = ee;
                dsum.x += ee.x; dsum.y += ee.y; dsum.z += ee.z; dsum.w += ee.w;
            }
            int e = 0;
            for (; e + 8 <= cn; e += 8) {
                int kk[8]; float fv[8], wv[8];
#pragma unroll
                for (int q = 0; q < 8; ++q) kk[q] = ldsK[wave][e + q];
#pragma unroll
                for (int q = 0; q < 8; ++q) fv[q] = bf2f(feat_all[kk[q] * 64 + lane]);
#pragma unroll
                for (int q = 0; q < 8; ++q) wv[q] = ldsE[wave][e + q][h];
#pragma unroll
                for (int q = 0; q < 8; ++q) acc += fv[q] * wv[q];
            }
            for (; e < cn; ++e)
                acc += bf2f(feat_all[ldsK[wave][e] * 64 + lane]) * ldsE[wave][e][h];
        }
#pragma unroll
        for (int m = 1; m < 64; m <<= 1) {
            dsum.x += __shfl_xor(dsum.x, m);
            dsum.y += __shfl_xor(dsum.y, m);
            dsum.z += __shfl_xor(dsum.z, m);
            dsum.w += __shfl_xor(dsum.w, m);
        }
        float invh = 1.f / fmaxf(h == 0 ? dsum.x : h == 1 ? dsum.y : h == 2 ? dsum.z : dsum.w,
                                 1e-16f);
        float o = acc * invh + bv;
        if (isf32) ((float*)out)[d * 64 + lane] = o;
        else       ((u16*)out)[d * 64 + lane] = f2bf(o);
    }
}

extern "C" void kernel_launch(void* const* d_in, const int* in_sizes, int n_in,
                              void* d_out, int out_size, void* d_ws, size_t ws_size,
                              hipStream_t stream)
{
    const void* x   = d_in[0];
    const int* srci = (const int*)d_in[1];
    const int* dsti = (const int*)d_in[2];
    const int* reli = (const int*)d_in[3];
    const void* cw  = d_in[4];
    const void* al  = d_in[5];
    const void* ar  = d_in[6];
    const void* hb  = d_in[7];

    // workspace layout (bytes, aligned), ~165.5 MB total
    char* ws = (char*)d_ws;
    u16*   feat_all = (u16*)  (ws + 0);            // 102,400,000
    float* el_all   = (float*)(ws + 102400000);    //  12,800,000
    float* er_all   = (float*)(ws + 115200000);    //  12,800,000
    int*   key_s    = (int*)  (ws + 128000000);    //   4,000,000
    int*   key_b    = (int*)  (ws + 132000000);    //   4,000,000
    f32x4* ew       = (f32x4*)(ws + 136000000);    //  16,000,000
    int*   off      = (int*)  (ws + 152000000);    //     400,064
    int*   histT    = (int*)  (ws + 152400064);    //     192,128
    int*   bsum     = (int*)  (ws + 152592192);    //         768
    int*   boff     = (int*)  (ws + 152592960);    //         768
    int*   bstart   = (int*)  (ws + 152593728);    //         832
    u16*   Bpre     = (u16*)  (ws + 152594560);    //      81,920
    u16*   xb       = (u16*)  (ws + 152676480);    //  12,800,000
    int*   flag     = (int*)  (ws + 165476480);    //           4

    k_detect<<<1, 64, 0, stream>>>((const u16*)x, flag);
    k_cvt<<<(NN * 8 + 255) / 256, 256, 0, stream>>>(x, flag, xb);
    k0_prep<<<(NR * 5120 + 255) / 256, 256, 0, stream>>>(cw, al, ar, flag, Bpre);
    k1_feat<<<dim3((NN + 63) / 64, NR), 256, 0, stream>>>(xb, Bpre, feat_all, el_all, er_all);
    k_binA<<<NBLK, 256, 0, stream>>>(dsti, histT);
    k_scanB1<<<NBB, 256, 0, stream>>>(histT, bsum);
    k_scanB2<<<1, 256, 0, stream>>>(bsum, boff);
    k_scanB3<<<NBB, 256, 0, stream>>>(boff, histT, bstart);
    k_binC<<<NBLK, 256, 0, stream>>>(srci, dsti, reli, histT, key_b);
    k_binD<<<NBUCK, 512, 0, stream>>>(bstart, key_b, key_s, off);
    k2e<<<NBUCK, 256, 0, stream>>>(bstart, key_s, el_all, er_all, ew);
    k3_node<<<(NN + 3) / 4, 256, 0, stream>>>(off, key_s, ew, feat_all, hb, flag, d_out);
}

// Round 8
// 231.339 us; speedup vs baseline: 1.0821x; 1.0821x over previous
//
#include <hip/hip_runtime.h>
#include <hip/hip_bf16.h>

#define NN 100000
#define NE 1000000
#define NR 8

// binned counting sort params
#define EB 4096
#define NBLK 245          // ceil(NE/EB)
#define NBUCK 196         // dst>>9 buckets
#define NT (NBUCK*NBLK)   // 48020 histogram cells
#define NBB 188           // ceil(NT/256)

typedef unsigned short u16;
typedef unsigned int u32;
typedef __attribute__((ext_vector_type(8))) short bf16x8;
typedef __attribute__((ext_vector_type(4))) float f32x4;

static __device__ __forceinline__ float bf2f(u16 u) {
    union { u32 i; float f; } v; v.i = ((u32)u) << 16; return v.f;
}
static __device__ __forceinline__ float bflo(u32 u) {
    union { u32 i; float f; } v; v.i = u << 16; return v.f;
}
static __device__ __forceinline__ float bfhi(u32 u) {
    union { u32 i; float f; } v; v.i = u & 0xffff0000u; return v.f;
}
static __device__ __forceinline__ u16 f2bf(float f) {
    __hip_bfloat16 h = __float2bfloat16(f);
    return *reinterpret_cast<u16*>(&h);
}
static __device__ __forceinline__ float ldf(const void* p, int idx, int isf32) {
    return isf32 ? ((const float*)p)[idx] : bf2f(((const u16*)p)[idx]);
}

// --------------------------------------------------------------------------
// dtype detect: bf16 N(0,1) words have sane exponents; fp32 mantissa words don't
// --------------------------------------------------------------------------
__global__ void k_detect(const u16* __restrict__ xw, int* __restrict__ flag)
{
    int t = threadIdx.x;
    int insane = 0;
    for (int k = t; k < 512; k += 64) {
        u16 w = xw[k];
        int ex = (w >> 7) & 0xFF;
        bool sane = ((w & 0x7FFF) == 0) || (ex >= 96 && ex <= 159);
        insane += sane ? 0 : 1;
    }
    for (int off = 32; off; off >>= 1) insane += __shfl_down(insane, off);
    if (t == 0) *flag = (insane > 50) ? 1 : 0;
}

// canonicalize x -> bf16 xb[NN*64]
__global__ void k_cvt(const void* __restrict__ xin, const int* __restrict__ flag,
                      u16* __restrict__ xb)
{
    int i = blockIdx.x * blockDim.x + threadIdx.x;   // 8 elems per thread
    if (i >= NN * 8) return;
    if (*flag) {
        const float* xf = (const float*)xin;
        u16 o[8];
#pragma unroll
        for (int j = 0; j < 8; ++j) o[j] = f2bf(xf[i * 8 + j]);
        uint4 v;
        v.x = (u32)o[0] | ((u32)o[1] << 16);
        v.y = (u32)o[2] | ((u32)o[3] << 16);
        v.z = (u32)o[4] | ((u32)o[5] << 16);
        v.w = (u32)o[6] | ((u32)o[7] << 16);
        ((uint4*)xb)[i] = v;
    } else {
        ((uint4*)xb)[i] = ((const uint4*)xin)[i];
    }
}

// --------------------------------------------------------------------------
// K0: swizzled B operand per relation in MFMA B-frag order
// --------------------------------------------------------------------------
__global__ void k0_prep(const void* __restrict__ cw, const void* __restrict__ al,
                        const void* __restrict__ ar, const int* __restrict__ flag,
                        u16* __restrict__ Bpre)
{
    int tid = blockIdx.x * blockDim.x + threadIdx.x;
    if (tid >= NR * 5120) return;
    int isf32 = *flag;
    int r = tid / 5120, rem = tid % 5120;
    int c = rem >> 3, j = rem & 7;
    int nt = c >> 7, kk = (c >> 6) & 1, lc = c & 63;
    int i = kk * 32 + ((lc >> 4) << 3) + j;
    int d = lc & 15;
    u16 val;
    if (nt < 4) {
        val = f2bf(ldf(cw, ((r * 4 + nt) * 64 + i) * 16 + d, isf32));
    } else if (d < 8) {
        int h = d >> 1;
        const void* attn = (d & 1) ? ar : al;
        float s = 0.f;
        for (int dd = 0; dd < 16; ++dd)
            s += ldf(cw, ((r * 4 + h) * 64 + i) * 16 + dd, isf32)
               * ldf(attn, (r * 4 + h) * 16 + dd, isf32);
        val = f2bf(s);
    } else {
        val = 0;
    }
    Bpre[tid] = val;
}

// --------------------------------------------------------------------------
// K1: feat_all[r][n][0:64] = x[n] @ W[r]  (+ el/er via appended 5th B tile)
// --------------------------------------------------------------------------
__global__ __launch_bounds__(256) void k1_feat(
    const u16* __restrict__ xb, const u16* __restrict__ Bpre,
    u16* __restrict__ feat_all, float* __restrict__ el_all, float* __restrict__ er_all)
{
    __shared__ alignas(16) u16 ldsA[4096];
    __shared__ alignas(16) u16 ldsB[5120];
    int n0 = blockIdx.x * 64;
    int r = blockIdx.y;
    int tid = threadIdx.x;
    int wave = tid >> 6, lane = tid & 63;

    for (int c = tid; c < 512; c += 256) {
        int mt = c >> 7, kk = (c >> 6) & 1, lc = c & 63;
        int node = n0 + mt * 16 + (lc & 15);
        if (node >= NN) node = NN - 1;
        int kbase = kk * 32 + ((lc >> 4) << 3);
        *(uint4*)&ldsA[c * 8] = *(const uint4*)&xb[node * 64 + kbase];
    }
    for (int c = tid; c < 640; c += 256)
        *(uint4*)&ldsB[c * 8] = *(const uint4*)&Bpre[r * 5120 + c * 8];
    __syncthreads();

    bf16x8 afrag0 = *(bf16x8*)&ldsA[((wave * 2 + 0) * 64 + lane) * 8];
    bf16x8 afrag1 = *(bf16x8*)&ldsA[((wave * 2 + 1) * 64 + lane) * 8];
    f32x4 acc[5];
#pragma unroll
    for (int nt = 0; nt < 5; ++nt) acc[nt] = f32x4{0.f, 0.f, 0.f, 0.f};
#pragma unroll
    for (int nt = 0; nt < 5; ++nt) {
        bf16x8 b0 = *(bf16x8*)&ldsB[((nt * 2 + 0) * 64 + lane) * 8];
        bf16x8 b1 = *(bf16x8*)&ldsB[((nt * 2 + 1) * 64 + lane) * 8];
        acc[nt] = __builtin_amdgcn_mfma_f32_16x16x32_bf16(afrag0, b0, acc[nt], 0, 0, 0);
        acc[nt] = __builtin_amdgcn_mfma_f32_16x16x32_bf16(afrag1, b1, acc[nt], 0, 0, 0);
    }

    int col = lane & 15, quad = lane >> 4;
    if (col < 8) {
        int h = col >> 1;
        float* dstp = (col & 1) ? er_all : el_all;
#pragma unroll
        for (int reg = 0; reg < 4; ++reg) {
            int node = n0 + wave * 16 + quad * 4 + reg;
            if (node < NN) dstp[(r * NN + node) * 4 + h] = acc[4][reg];
        }
    }
    __syncthreads();
#pragma unroll
    for (int nt = 0; nt < 4; ++nt) {
        int cg = nt * 16 + col;
#pragma unroll
        for (int reg = 0; reg < 4; ++reg) {
            int row = quad * 4 + reg;
            ldsA[(wave * 16 + row) * 64 + cg] = f2bf(acc[nt][reg]);
        }
    }
    __syncthreads();
    for (int c = tid; c < 512; c += 256) {
        int nl = c >> 3, part = c & 7;
        int node = n0 + nl;
        if (node < NN)
            *(uint4*)&feat_all[(r * NN + node) * 64 + part * 8] = *(uint4*)&ldsA[c * 8];
    }
}

// --------------------------------------------------------------------------
// Binned counting sort by dst — no global atomics, coalesced writes.
// --------------------------------------------------------------------------
__global__ __launch_bounds__(256) void k_binA(const int* __restrict__ dsti,
                                              int* __restrict__ histT)
{
    __shared__ int hist[NBUCK];
    int t = threadIdx.x, blk = blockIdx.x;
    if (t < NBUCK) hist[t] = 0;
    __syncthreads();
    int base = blk * EB;
    for (int j = 0; j < EB; j += 256) {
        int e = base + j + t;
        if (e < NE) atomicAdd(&hist[dsti[e] >> 9], 1);
    }
    __syncthreads();
    if (t < NBUCK) histT[t * NBLK + blk] = hist[t];
}

__global__ __launch_bounds__(256) void k_scanB1(int* __restrict__ histT,
                                                int* __restrict__ bsum)
{
    __shared__ int wtot[4];
    int t = threadIdx.x;
    int gi = blockIdx.x * 256 + t;
    int v = (gi < NT) ? histT[gi] : 0;
    int lane = t & 63, w = t >> 6;
    int s = v;
#pragma unroll
    for (int m = 1; m < 64; m <<= 1) {
        int u = __shfl_up(s, m);
        if (lane >= m) s += u;
    }
    if (lane == 63) wtot[w] = s;
    __syncthreads();
    int wb = 0;
    for (int i = 0; i < w; ++i) wb += wtot[i];
    if (gi < NT) histT[gi] = wb + s - v;
    if (t == 255) bsum[blockIdx.x] = wb + s;
}

__global__ __launch_bounds__(256) void k_scanB2(const int* __restrict__ bsum,
                                                int* __restrict__ boff)
{
    __shared__ int wtot[4];
    int t = threadIdx.x;
    int v = (t < NBB) ? bsum[t] : 0;
    int lane = t & 63, w = t >> 6;
    int s = v;
#pragma unroll
    for (int m = 1; m < 64; m <<= 1) {
        int u = __shfl_up(s, m);
        if (lane >= m) s += u;
    }
    if (lane == 63) wtot[w] = s;
    __syncthreads();
    int wb = 0;
    for (int i = 0; i < w; ++i) wb += wtot[i];
    if (t < NBB) boff[t] = wb + s - v;
}

__global__ __launch_bounds__(256) void k_scanB3(const int* __restrict__ boff,
                                                int* __restrict__ histT,
                                                int* __restrict__ bstart)
{
    int gi = blockIdx.x * 256 + threadIdx.x;
    if (gi < NT) {
        int val = histT[gi] + boff[blockIdx.x];
        histT[gi] = val;
        if (gi % NBLK == 0) bstart[gi / NBLK] = val;
    }
    if (gi == 0) bstart[NBUCK] = NE;
}

// key = (dst&511)<<20 | rel<<17 | src   (29 bits)
__global__ __launch_bounds__(256) void k_binC(
    const int* __restrict__ srci, const int* __restrict__ dsti,
    const int* __restrict__ reli, const int* __restrict__ histT,
    int* __restrict__ key_b)
{
    __shared__ int cur[NBUCK];
    int t = threadIdx.x, blk = blockIdx.x;
    if (t < NBUCK) cur[t] = histT[t * NBLK + blk];
    __syncthreads();
    int base = blk * EB;
    for (int j = 0; j < EB; j += 256) {
        int e = base + j + t;
        if (e < NE) {
            int d = dsti[e];
            int key = ((d & 511) << 20) | (reli[e] << 17) | srci[e];
            int pos = atomicAdd(&cur[d >> 9], 1);
            key_b[pos] = key;
        }
    }
}

__global__ __launch_bounds__(512) void k_binD(
    const int* __restrict__ bstart, const int* __restrict__ key_b,
    int* __restrict__ key_s, int* __restrict__ off)
{
    __shared__ int cnt[512];
    __shared__ int wtot[8];
    int t = threadIdx.x, b = blockIdx.x;
    int s0 = bstart[b], s1 = bstart[b + 1];
    cnt[t] = 0;
    __syncthreads();
    for (int j = s0 + t; j < s1; j += 512)
        atomicAdd(&cnt[(key_b[j] >> 20) & 511], 1);
    __syncthreads();
    int v = cnt[t];
    int lane = t & 63, w = t >> 6;
    int s = v;
#pragma unroll
    for (int m = 1; m < 64; m <<= 1) {
        int u = __shfl_up(s, m);
        if (lane >= m) s += u;
    }
    if (lane == 63) wtot[w] = s;
    __syncthreads();
    int wb = 0;
    for (int i = 0; i < w; ++i) wb += wtot[i];
    int excl = s0 + wb + s - v;
    int d = (b << 9) + t;
    if (d < NN) off[d] = excl;
    __syncthreads();
    cnt[t] = excl;
    if (b == 0 && t == 0) off[NN] = NE;
    __syncthreads();
    for (int j = s0 + t; j < s1; j += 512) {
        int key = key_b[j];
        int pos = atomicAdd(&cnt[(key >> 20) & 511], 1);
        key_s[pos] = key;
    }
}

// --------------------------------------------------------------------------
// K3: one wave per dst node, single pass.
// Stage (per 64-edge chunk): decode key, gather el/er, ee=exp(leaky(el+er))
//   -> LDS (tail zero-filled so the inner loop needs no masking).
// Inner loop: 4 edges per wave-instruction. lane = eg(2b) x fl(4b):
//   lane handles edge (e+eg), features 4*fl..4*fl+3 via one 8B load.
//   accW accumulates the weight sum (denominator) for free.
// Reduce: shfl_xor over eg bits; scale by 1/denom; eg==0 lanes store 8B.
// --------------------------------------------------------------------------
__global__ __launch_bounds__(256) void k3_node(
    const int* __restrict__ off, const int* __restrict__ key_s,
    const float* __restrict__ el_all, const float* __restrict__ er_all,
    const u16* __restrict__ feat_all, const void* __restrict__ bias,
    const int* __restrict__ flag, void* __restrict__ out)
{
    __shared__ int   ldsK[4][64];
    __shared__ float ldsE[4][64][4];
    int wave = threadIdx.x >> 6, lane = threadIdx.x & 63;
    int eg = lane >> 4;          // edge subclass 0..3
    int fl = lane & 15;          // feature quad: features 4*fl .. 4*fl+3
    int h  = fl >> 2;            // head of those features
    int gw = blockIdx.x * 4 + wave;
    int nw = gridDim.x * 4;
    int isf32 = *flag;
    float bv0 = ldf(bias, fl * 4 + 0, isf32);
    float bv1 = ldf(bias, fl * 4 + 1, isf32);
    float bv2 = ldf(bias, fl * 4 + 2, isf32);
    float bv3 = ldf(bias, fl * 4 + 3, isf32);

    for (int d = gw; d < NN; d += nw) {
        int start = off[d], end = off[d + 1];
        int deg = end - start;

        float acc0 = 0.f, acc1 = 0.f, acc2 = 0.f, acc3 = 0.f, accW = 0.f;
        for (int base = 0; base < deg; base += 64) {
            int cn = min(64, deg - base);
            // stage chunk (zero-fill tail)
            if (lane < cn) {
                int key = key_s[start + base + lane];
                int rel = (key >> 17) & 7, src = key & 131071;
                int kk = rel * NN + src;
                f32x4 el = *(const f32x4*)&el_all[kk * 4];
                f32x4 er = *(const f32x4*)&er_all[(rel * NN + d) * 4];
                f32x4 ee;
#pragma unroll
                for (int q = 0; q < 4; ++q) {
                    float v = el[q] + er[q];
                    v = v > 0.f ? v : 0.2f * v;
                    ee[q] = __expf(v);
                }
                ldsK[wave][lane] = kk;
                *(f32x4*)&ldsE[wave][lane][0] = ee;
            } else {
                ldsK[wave][lane] = 0;
                *(f32x4*)&ldsE[wave][lane][0] = f32x4{0.f, 0.f, 0.f, 0.f};
            }
            int cnr = (cn + 3) & ~3;
            for (int e = 0; e < cnr; e += 4) {
                int   ke = ldsK[wave][e + eg];
                float w  = ldsE[wave][e + eg][h];
                uint2 u  = *(const uint2*)&feat_all[ke * 64 + fl * 4];
                acc0 += bflo(u.x) * w;
                acc1 += bfhi(u.x) * w;
                acc2 += bflo(u.y) * w;
                acc3 += bfhi(u.y) * w;
                accW += w;
            }
        }
        // reduce across the 4 edge subclasses (lanes differing in bits 4,5)
#pragma unroll
        for (int m = 16; m < 64; m <<= 1) {
            acc0 += __shfl_xor(acc0, m);
            acc1 += __shfl_xor(acc1, m);
            acc2 += __shfl_xor(acc2, m);
            acc3 += __shfl_xor(acc3, m);
            accW += __shfl_xor(accW, m);
        }
        float invh = 1.f / fmaxf(accW, 1e-16f);
        if (eg == 0) {
            float o0 = acc0 * invh + bv0;
            float o1 = acc1 * invh + bv1;
            float o2 = acc2 * invh + bv2;
            float o3 = acc3 * invh + bv3;
            if (isf32) {
                ((f32x4*)out)[d * 16 + fl] = f32x4{o0, o1, o2, o3};
            } else {
                uint2 st;
                st.x = (u32)f2bf(o0) | ((u32)f2bf(o1) << 16);
                st.y = (u32)f2bf(o2) | ((u32)f2bf(o3) << 16);
                *(uint2*)&((u16*)out)[d * 64 + fl * 4] = st;
            }
        }
    }
}

extern "C" void kernel_launch(void* const* d_in, const int* in_sizes, int n_in,
                              void* d_out, int out_size, void* d_ws, size_t ws_size,
                              hipStream_t stream)
{
    const void* x   = d_in[0];
    const int* srci = (const int*)d_in[1];
    const int* dsti = (const int*)d_in[2];
    const int* reli = (const int*)d_in[3];
    const void* cw  = d_in[4];
    const void* al  = d_in[5];
    const void* ar  = d_in[6];
    const void* hb  = d_in[7];

    // workspace layout (bytes, aligned), ~149.5 MB total
    char* ws = (char*)d_ws;
    u16*   feat_all = (u16*)  (ws + 0);            // 102,400,000
    float* el_all   = (float*)(ws + 102400000);    //  12,800,000
    float* er_all   = (float*)(ws + 115200000);    //  12,800,000
    int*   key_s    = (int*)  (ws + 128000000);    //   4,000,000
    int*   key_b    = (int*)  (ws + 132000000);    //   4,000,000
    int*   off      = (int*)  (ws + 136000000);    //     400,064
    int*   histT    = (int*)  (ws + 136400064);    //     192,128
    int*   bsum     = (int*)  (ws + 136592192);    //         768
    int*   boff     = (int*)  (ws + 136592960);    //         768
    int*   bstart   = (int*)  (ws + 136593728);    //         832
    u16*   Bpre     = (u16*)  (ws + 136594560);    //      81,920
    u16*   xb       = (u16*)  (ws + 136676480);    //  12,800,000
    int*   flag     = (int*)  (ws + 149476480);    //           4

    k_detect<<<1, 64, 0, stream>>>((const u16*)x, flag);
    k_cvt<<<(NN * 8 + 255) / 256, 256, 0, stream>>>(x, flag, xb);
    k0_prep<<<(NR * 5120 + 255) / 256, 256, 0, stream>>>(cw, al, ar, flag, Bpre);
    k1_feat<<<dim3((NN + 63) / 64, NR), 256, 0, stream>>>(xb, Bpre, feat_all, el_all, er_all);
    k_binA<<<NBLK, 256, 0, stream>>>(dsti, histT);
    k_scanB1<<<NBB, 256, 0, stream>>>(histT, bsum);
    k_scanB2<<<1, 256, 0, stream>>>(bsum, boff);
    k_scanB3<<<NBB, 256, 0, stream>>>(boff, histT, bstart);
    k_binC<<<NBLK, 256, 0, stream>>>(srci, dsti, reli, histT, key_b);
    k_binD<<<NBUCK, 512, 0, stream>>>(bstart, key_b, key_s, off);
    k3_node<<<(NN + 3) / 4, 256, 0, stream>>>(off, key_s, el_all, er_all, feat_all,
                                              hb, flag, d_out);
}

// Round 9
// 229.872 us; speedup vs baseline: 1.0890x; 1.0064x over previous
//
#include <hip/hip_runtime.h>
#include <hip/hip_bf16.h>

#define NN 100000
#define NE 1000000
#define NR 8

// binned counting sort params
#define EB 4096
#define NBLK 245          // ceil(NE/EB)
#define NBUCK 196         // dst>>9 buckets
#define NT (NBUCK*NBLK)   // 48020 histogram cells
#define NBB 188           // ceil(NT/256)

#define CAP 256           // staged edges per wave in k3 (16 dsts, mean 160, sd 12.6)

typedef unsigned short u16;
typedef unsigned int u32;
typedef __attribute__((ext_vector_type(8))) short bf16x8;
typedef __attribute__((ext_vector_type(4))) float f32x4;

static __device__ __forceinline__ float bf2f(u16 u) {
    union { u32 i; float f; } v; v.i = ((u32)u) << 16; return v.f;
}
static __device__ __forceinline__ float bflo(u32 u) {
    union { u32 i; float f; } v; v.i = u << 16; return v.f;
}
static __device__ __forceinline__ float bfhi(u32 u) {
    union { u32 i; float f; } v; v.i = u & 0xffff0000u; return v.f;
}
static __device__ __forceinline__ u16 f2bf(float f) {
    __hip_bfloat16 h = __float2bfloat16(f);
    return *reinterpret_cast<u16*>(&h);
}
static __device__ __forceinline__ float ldf(const void* p, int idx, int isf32) {
    return isf32 ? ((const float*)p)[idx] : bf2f(((const u16*)p)[idx]);
}

// detect helper: one wave scans first 512 u16 words of x; returns 1 if fp32
static __device__ __forceinline__ int detect_wave(const u16* xw, int lane)
{
    int insane = 0;
    for (int k = lane; k < 512; k += 64) {
        u16 w = xw[k];
        int ex = (w >> 7) & 0xFF;
        bool sane = ((w & 0x7FFF) == 0) || (ex >= 96 && ex <= 159);
        insane += sane ? 0 : 1;
    }
    for (int off = 32; off; off >>= 1) insane += __shfl_down(insane, off);
    return insane;   // valid in lane 0
}

// --------------------------------------------------------------------------
// k_cvt: canonicalize x -> bf16 xb  (detect fused; block 0 publishes flag)
// --------------------------------------------------------------------------
__global__ __launch_bounds__(256) void k_cvt(const void* __restrict__ xin,
                                             u16* __restrict__ xb, int* __restrict__ flag)
{
    __shared__ int sflag;
    int t = threadIdx.x;
    if (t < 64) {
        int insane = detect_wave((const u16*)xin, t);
        if (t == 0) {
            sflag = (insane > 50) ? 1 : 0;
            if (blockIdx.x == 0) *flag = sflag;
        }
    }
    __syncthreads();
    int isf32 = sflag;
    int i = blockIdx.x * 256 + t;
    if (i >= NN * 8) return;
    if (isf32) {
        const float* xf = (const float*)xin;
        u16 o[8];
#pragma unroll
        for (int j = 0; j < 8; ++j) o[j] = f2bf(xf[i * 8 + j]);
        uint4 v;
        v.x = (u32)o[0] | ((u32)o[1] << 16);
        v.y = (u32)o[2] | ((u32)o[3] << 16);
        v.z = (u32)o[4] | ((u32)o[5] << 16);
        v.w = (u32)o[6] | ((u32)o[7] << 16);
        ((uint4*)xb)[i] = v;
    } else {
        ((uint4*)xb)[i] = ((const uint4*)xin)[i];
    }
}

// --------------------------------------------------------------------------
// K0: swizzled B operand per relation in MFMA B-frag order (detect fused)
// --------------------------------------------------------------------------
__global__ __launch_bounds__(256) void k0_prep(const void* __restrict__ xin,
                        const void* __restrict__ cw, const void* __restrict__ al,
                        const void* __restrict__ ar, u16* __restrict__ Bpre)
{
    __shared__ int sflag;
    int t = threadIdx.x;
    if (t < 64) {
        int insane = detect_wave((const u16*)xin, t);
        if (t == 0) sflag = (insane > 50) ? 1 : 0;
    }
    __syncthreads();
    int isf32 = sflag;
    int tid = blockIdx.x * 256 + t;
    if (tid >= NR * 5120) return;
    int r = tid / 5120, rem = tid % 5120;
    int c = rem >> 3, j = rem & 7;
    int nt = c >> 7, kk = (c >> 6) & 1, lc = c & 63;
    int i = kk * 32 + ((lc >> 4) << 3) + j;
    int d = lc & 15;
    u16 val;
    if (nt < 4) {
        val = f2bf(ldf(cw, ((r * 4 + nt) * 64 + i) * 16 + d, isf32));
    } else if (d < 8) {
        int h = d >> 1;
        const void* attn = (d & 1) ? ar : al;
        float s = 0.f;
        for (int dd = 0; dd < 16; ++dd)
            s += ldf(cw, ((r * 4 + h) * 64 + i) * 16 + dd, isf32)
               * ldf(attn, (r * 4 + h) * 16 + dd, isf32);
        val = f2bf(s);
    } else {
        val = 0;
    }
    Bpre[tid] = val;
}

// --------------------------------------------------------------------------
// K1: feat_all[r][n][0:64] = x[n] @ W[r]  (+ el/er via appended 5th B tile)
// --------------------------------------------------------------------------
__global__ __launch_bounds__(256) void k1_feat(
    const u16* __restrict__ xb, const u16* __restrict__ Bpre,
    u16* __restrict__ feat_all, float* __restrict__ el_all, float* __restrict__ er_all)
{
    __shared__ alignas(16) u16 ldsA[4096];
    __shared__ alignas(16) u16 ldsB[5120];
    int n0 = blockIdx.x * 64;
    int r = blockIdx.y;
    int tid = threadIdx.x;
    int wave = tid >> 6, lane = tid & 63;

    for (int c = tid; c < 512; c += 256) {
        int mt = c >> 7, kk = (c >> 6) & 1, lc = c & 63;
        int node = n0 + mt * 16 + (lc & 15);
        if (node >= NN) node = NN - 1;
        int kbase = kk * 32 + ((lc >> 4) << 3);
        *(uint4*)&ldsA[c * 8] = *(const uint4*)&xb[node * 64 + kbase];
    }
    for (int c = tid; c < 640; c += 256)
        *(uint4*)&ldsB[c * 8] = *(const uint4*)&Bpre[r * 5120 + c * 8];
    __syncthreads();

    bf16x8 afrag0 = *(bf16x8*)&ldsA[((wave * 2 + 0) * 64 + lane) * 8];
    bf16x8 afrag1 = *(bf16x8*)&ldsA[((wave * 2 + 1) * 64 + lane) * 8];
    f32x4 acc[5];
#pragma unroll
    for (int nt = 0; nt < 5; ++nt) acc[nt] = f32x4{0.f, 0.f, 0.f, 0.f};
#pragma unroll
    for (int nt = 0; nt < 5; ++nt) {
        bf16x8 b0 = *(bf16x8*)&ldsB[((nt * 2 + 0) * 64 + lane) * 8];
        bf16x8 b1 = *(bf16x8*)&ldsB[((nt * 2 + 1) * 64 + lane) * 8];
        acc[nt] = __builtin_amdgcn_mfma_f32_16x16x32_bf16(afrag0, b0, acc[nt], 0, 0, 0);
        acc[nt] = __builtin_amdgcn_mfma_f32_16x16x32_bf16(afrag1, b1, acc[nt], 0, 0, 0);
    }

    int col = lane & 15, quad = lane >> 4;
    if (col < 8) {
        int h = col >> 1;
        float* dstp = (col & 1) ? er_all : el_all;
#pragma unroll
        for (int reg = 0; reg < 4; ++reg) {
            int node = n0 + wave * 16 + quad * 4 + reg;
            if (node < NN) dstp[(r * NN + node) * 4 + h] = acc[4][reg];
        }
    }
    __syncthreads();
#pragma unroll
    for (int nt = 0; nt < 4; ++nt) {
        int cg = nt * 16 + col;
#pragma unroll
        for (int reg = 0; reg < 4; ++reg) {
            int row = quad * 4 + reg;
            ldsA[(wave * 16 + row) * 64 + cg] = f2bf(acc[nt][reg]);
        }
    }
    __syncthreads();
    for (int c = tid; c < 512; c += 256) {
        int nl = c >> 3, part = c & 7;
        int node = n0 + nl;
        if (node < NN)
            *(uint4*)&feat_all[(r * NN + node) * 64 + part * 8] = *(uint4*)&ldsA[c * 8];
    }
}

// --------------------------------------------------------------------------
// Binned counting sort by dst — no global atomics, coalesced writes.
// --------------------------------------------------------------------------
__global__ __launch_bounds__(256) void k_binA(const int* __restrict__ dsti,
                                              int* __restrict__ histT)
{
    __shared__ int hist[NBUCK];
    int t = threadIdx.x, blk = blockIdx.x;
    if (t < NBUCK) hist[t] = 0;
    __syncthreads();
    int base = blk * EB;
    for (int j = 0; j < EB; j += 256) {
        int e = base + j + t;
        if (e < NE) atomicAdd(&hist[dsti[e] >> 9], 1);
    }
    __syncthreads();
    if (t < NBUCK) histT[t * NBLK + blk] = hist[t];
}

__global__ __launch_bounds__(256) void k_scanB1(int* __restrict__ histT,
                                                int* __restrict__ bsum)
{
    __shared__ int wtot[4];
    int t = threadIdx.x;
    int gi = blockIdx.x * 256 + t;
    int v = (gi < NT) ? histT[gi] : 0;
    int lane = t & 63, w = t >> 6;
    int s = v;
#pragma unroll
    for (int m = 1; m < 64; m <<= 1) {
        int u = __shfl_up(s, m);
        if (lane >= m) s += u;
    }
    if (lane == 63) wtot[w] = s;
    __syncthreads();
    int wb = 0;
    for (int i = 0; i < w; ++i) wb += wtot[i];
    if (gi < NT) histT[gi] = wb + s - v;
    if (t == 255) bsum[blockIdx.x] = wb + s;
}

__global__ __launch_bounds__(256) void k_scanB2(const int* __restrict__ bsum,
                                                int* __restrict__ boff)
{
    __shared__ int wtot[4];
    int t = threadIdx.x;
    int v = (t < NBB) ? bsum[t] : 0;
    int lane = t & 63, w = t >> 6;
    int s = v;
#pragma unroll
    for (int m = 1; m < 64; m <<= 1) {
        int u = __shfl_up(s, m);
        if (lane >= m) s += u;
    }
    if (lane == 63) wtot[w] = s;
    __syncthreads();
    int wb = 0;
    for (int i = 0; i < w; ++i) wb += wtot[i];
    if (t < NBB) boff[t] = wb + s - v;
}

__global__ __launch_bounds__(256) void k_scanB3(const int* __restrict__ boff,
                                                int* __restrict__ histT,
                                                int* __restrict__ bstart)
{
    int gi = blockIdx.x * 256 + threadIdx.x;
    if (gi < NT) {
        int val = histT[gi] + boff[blockIdx.x];
        histT[gi] = val;
        if (gi % NBLK == 0) bstart[gi / NBLK] = val;
    }
    if (gi == 0) bstart[NBUCK] = NE;
}

// key = (dst&511)<<20 | rel<<17 | src   (29 bits)
__global__ __launch_bounds__(256) void k_binC(
    const int* __restrict__ srci, const int* __restrict__ dsti,
    const int* __restrict__ reli, const int* __restrict__ histT,
    int* __restrict__ key_b)
{
    __shared__ int cur[NBUCK];
    int t = threadIdx.x, blk = blockIdx.x;
    if (t < NBUCK) cur[t] = histT[t * NBLK + blk];
    __syncthreads();
    int base = blk * EB;
    for (int j = 0; j < EB; j += 256) {
        int e = base + j + t;
        if (e < NE) {
            int d = dsti[e];
            int key = ((d & 511) << 20) | (reli[e] << 17) | srci[e];
            int pos = atomicAdd(&cur[d >> 9], 1);
            key_b[pos] = key;
        }
    }
}

__global__ __launch_bounds__(512) void k_binD(
    const int* __restrict__ bstart, const int* __restrict__ key_b,
    int* __restrict__ key_s, int* __restrict__ off)
{
    __shared__ int cnt[512];
    __shared__ int wtot[8];
    int t = threadIdx.x, b = blockIdx.x;
    int s0 = bstart[b], s1 = bstart[b + 1];
    cnt[t] = 0;
    __syncthreads();
    for (int j = s0 + t; j < s1; j += 512)
        atomicAdd(&cnt[(key_b[j] >> 20) & 511], 1);
    __syncthreads();
    int v = cnt[t];
    int lane = t & 63, w = t >> 6;
    int s = v;
#pragma unroll
    for (int m = 1; m < 64; m <<= 1) {
        int u = __shfl_up(s, m);
        if (lane >= m) s += u;
    }
    if (lane == 63) wtot[w] = s;
    __syncthreads();
    int wb = 0;
    for (int i = 0; i < w; ++i) wb += wtot[i];
    int excl = s0 + wb + s - v;
    int d = (b << 9) + t;
    if (d < NN) off[d] = excl;
    __syncthreads();
    cnt[t] = excl;
    if (b == 0 && t == 0) off[NN] = NE;
    __syncthreads();
    for (int j = s0 + t; j < s1; j += 512) {
        int key = key_b[j];
        int pos = atomicAdd(&cnt[(key >> 20) & 511], 1);
        key_s[pos] = key;
    }
}

// --------------------------------------------------------------------------
// K3 v3: block = 64 consecutive dsts, wave = 16 contiguous dsts.
//  - er for all 64 dsts x 8 rels preloaded coalesced into LDS (8KB)
//  - wave stages its contiguous edge run (avg 160) with 64-lane parallelism:
//    coalesced key reads, el gathers, exp -> LDS key+ee
//  - per node: eg/fl inner loop, 4 independent 8B feat loads in flight,
//    denominator accumulated for free, 10-shuffle reduce, 8B store
// --------------------------------------------------------------------------
__global__ __launch_bounds__(256) void k3_node(
    const int* __restrict__ off, const int* __restrict__ key_s,
    const float* __restrict__ el_all, const float* __restrict__ er_all,
    const u16* __restrict__ feat_all, const void* __restrict__ bias,
    const int* __restrict__ flag, void* __restrict__ out)
{
    __shared__ float ldsER[64][8][4];    // 8KB
    __shared__ int   ldsOffs[65];
    __shared__ int   ldsKey[4][CAP];     // 4KB
    __shared__ float ldsEE[4][CAP][4];   // 16KB
    int t = threadIdx.x;
    int wave = t >> 6, lane = t & 63;
    int eg = lane >> 4;          // edge subclass 0..3
    int fl = lane & 15;          // feature quad
    int h  = fl >> 2;            // head
    int d0 = blockIdx.x * 64;
    int isf32 = *flag;

    // preload er (coalesced 1KB per relation)
#pragma unroll
    for (int r = 0; r < 8; ++r) {
        int dl = t >> 2, q = t & 3;
        int dd = d0 + dl; if (dd >= NN) dd = NN - 1;
        ldsER[dl][r][q] = er_all[(r * NN + dd) * 4 + q];
    }
    if (t < 65) ldsOffs[t] = off[min(d0 + t, NN)];
    __syncthreads();

    int dlo = wave * 16;
    int estart = ldsOffs[dlo], eend = ldsOffs[dlo + 16];
    int count = eend - estart;
    int scount = min(count, CAP);

    // stage this wave's edges (coalesced keys, parallel el gathers + exp)
    for (int j = lane; j < scount; j += 64) {
        int key = key_s[estart + j];
        int rel = (key >> 17) & 7, src = key & 131071;
        int dl = (key >> 20) & 63;
        int kk = rel * NN + src;
        f32x4 el = *(const f32x4*)&el_all[kk * 4];
        f32x4 er = *(const f32x4*)&ldsER[dl][rel][0];
        f32x4 ee;
#pragma unroll
        for (int q = 0; q < 4; ++q) {
            float v = el[q] + er[q];
            v = v > 0.f ? v : 0.2f * v;
            ee[q] = __expf(v);
        }
        ldsKey[wave][j] = kk;
        *(f32x4*)&ldsEE[wave][j][0] = ee;
    }
    // same-wave LDS write->read: ordered via lgkmcnt

    float bv0 = ldf(bias, fl * 4 + 0, isf32);
    float bv1 = ldf(bias, fl * 4 + 1, isf32);
    float bv2 = ldf(bias, fl * 4 + 2, isf32);
    float bv3 = ldf(bias, fl * 4 + 3, isf32);

    for (int nl = 0; nl < 16; ++nl) {
        int d = d0 + dlo + nl;
        if (d >= NN) break;
        int s  = ldsOffs[dlo + nl] - estart;
        int e1 = ldsOffs[dlo + nl + 1] - estart;
        float acc0 = 0.f, acc1 = 0.f, acc2 = 0.f, acc3 = 0.f, accW = 0.f;

        int e1c = min(e1, CAP);
        for (int base = s; base < e1c; base += 16) {
            int kk[4]; float w[4];
#pragma unroll
            for (int q = 0; q < 4; ++q) {
                int idx = base + q * 4 + eg;
                bool vld = idx < e1c;
                kk[q] = vld ? ldsKey[wave][idx] : 0;
                w[q]  = vld ? ldsEE[wave][idx][h] : 0.f;
            }
            uint2 u[4];
#pragma unroll
            for (int q = 0; q < 4; ++q)
                u[q] = *(const uint2*)&feat_all[kk[q] * 64 + fl * 4];
#pragma unroll
            for (int q = 0; q < 4; ++q) {
                acc0 += bflo(u[q].x) * w[q];
                acc1 += bfhi(u[q].x) * w[q];
                acc2 += bflo(u[q].y) * w[q];
                acc3 += bfhi(u[q].y) * w[q];
                accW += w[q];
            }
        }
        // overflow path (statistically never; correctness fallback)
        for (int base = max(s, CAP); base < e1; base += 4) {
            int idx = base + eg;
            int kk0 = 0; float w0 = 0.f;
            if (idx < e1) {
                int key = key_s[estart + idx];
                int rel = (key >> 17) & 7, src = key & 131071;
                kk0 = rel * NN + src;
                int dl = (key >> 20) & 63;
                float v = el_all[kk0 * 4 + h] + ldsER[dl][rel][h];
                v = v > 0.f ? v : 0.2f * v;
                w0 = __expf(v);
            }
            uint2 u = *(const uint2*)&feat_all[kk0 * 64 + fl * 4];
            acc0 += bflo(u.x) * w0;
            acc1 += bfhi(u.x) * w0;
            acc2 += bflo(u.y) * w0;
            acc3 += bfhi(u.y) * w0;
            accW += w0;
        }

#pragma unroll
        for (int m = 16; m < 64; m <<= 1) {
            acc0 += __shfl_xor(acc0, m);
            acc1 += __shfl_xor(acc1, m);
            acc2 += __shfl_xor(acc2, m);
            acc3 += __shfl_xor(acc3, m);
            accW += __shfl_xor(accW, m);
        }
        float invh = 1.f / fmaxf(accW, 1e-16f);
        if (eg == 0) {
            float o0 = acc0 * invh + bv0;
            float o1 = acc1 * invh + bv1;
            float o2 = acc2 * invh + bv2;
            float o3 = acc3 * invh + bv3;
            if (isf32) {
                ((f32x4*)out)[d * 16 + fl] = f32x4{o0, o1, o2, o3};
            } else {
                uint2 st;
                st.x = (u32)f2bf(o0) | ((u32)f2bf(o1) << 16);
                st.y = (u32)f2bf(o2) | ((u32)f2bf(o3) << 16);
                *(uint2*)&((u16*)out)[d * 64 + fl * 4] = st;
            }
        }
    }
}

extern "C" void kernel_launch(void* const* d_in, const int* in_sizes, int n_in,
                              void* d_out, int out_size, void* d_ws, size_t ws_size,
                              hipStream_t stream)
{
    const void* x   = d_in[0];
    const int* srci = (const int*)d_in[1];
    const int* dsti = (const int*)d_in[2];
    const int* reli = (const int*)d_in[3];
    const void* cw  = d_in[4];
    const void* al  = d_in[5];
    const void* ar  = d_in[6];
    const void* hb  = d_in[7];

    // workspace layout (bytes, aligned), ~149.5 MB total
    char* ws = (char*)d_ws;
    u16*   feat_all = (u16*)  (ws + 0);            // 102,400,000
    float* el_all   = (float*)(ws + 102400000);    //  12,800,000
    float* er_all   = (float*)(ws + 115200000);    //  12,800,000
    int*   key_s    = (int*)  (ws + 128000000);    //   4,000,000
    int*   key_b    = (int*)  (ws + 132000000);    //   4,000,000
    int*   off      = (int*)  (ws + 136000000);    //     400,064
    int*   histT    = (int*)  (ws + 136400064);    //     192,128
    int*   bsum     = (int*)  (ws + 136592192);    //         768
    int*   boff     = (int*)  (ws + 136592960);    //         768
    int*   bstart   = (int*)  (ws + 136593728);    //         832
    u16*   Bpre     = (u16*)  (ws + 136594560);    //      81,920
    u16*   xb       = (u16*)  (ws + 136676480);    //  12,800,000
    int*   flag     = (int*)  (ws + 149476480);    //           4

    k_cvt<<<(NN * 8 + 255) / 256, 256, 0, stream>>>(x, xb, flag);
    k0_prep<<<(NR * 5120 + 255) / 256, 256, 0, stream>>>(x, cw, al, ar, Bpre);
    k1_feat<<<dim3((NN + 63) / 64, NR), 256, 0, stream>>>(xb, Bpre, feat_all, el_all, er_all);
    k_binA<<<NBLK, 256, 0, stream>>>(dsti, histT);
    k_scanB1<<<NBB, 256, 0, stream>>>(histT, bsum);
    k_scanB2<<<1, 256, 0, stream>>>(bsum, boff);
    k_scanB3<<<NBB, 256, 0, stream>>>(boff, histT, bstart);
    k_binC<<<NBLK, 256, 0, stream>>>(srci, dsti, reli, histT, key_b);
    k_binD<<<NBUCK, 512, 0, stream>>>(bstart, key_b, key_s, off);
    k3_node<<<(NN + 63) / 64, 256, 0, stream>>>(off, key_s, el_all, er_all, feat_all,
                                                hb, flag, d_out);
}

// Round 10
// 220.587 us; speedup vs baseline: 1.1348x; 1.0421x over previous
//
#include <hip/hip_runtime.h>
#include <hip/hip_bf16.h>

#define NN 100000
#define NE 1000000
#define NR 8

// binned counting sort params
#define EB 1024
#define NBLK 977          // ceil(NE/EB)
#define NBUCK 196         // dst>>9 buckets
#define NT (NBUCK*NBLK)   // 191492 histogram cells
#define NBB 749           // ceil(NT/256)

#define CAP 224           // staged edges per wave in k3 (16 dsts, mean 160, sd 12.6)

typedef unsigned short u16;
typedef unsigned int u32;
typedef __attribute__((ext_vector_type(8))) short bf16x8;
typedef __attribute__((ext_vector_type(4))) float f32x4;

static __device__ __forceinline__ float bf2f(u16 u) {
    union { u32 i; float f; } v; v.i = ((u32)u) << 16; return v.f;
}
static __device__ __forceinline__ float bflo(u32 u) {
    union { u32 i; float f; } v; v.i = u << 16; return v.f;
}
static __device__ __forceinline__ float bfhi(u32 u) {
    union { u32 i; float f; } v; v.i = u & 0xffff0000u; return v.f;
}
static __device__ __forceinline__ u16 f2bf(float f) {
    __hip_bfloat16 h = __float2bfloat16(f);
    return *reinterpret_cast<u16*>(&h);
}
static __device__ __forceinline__ float ldf(const void* p, int idx, int isf32) {
    return isf32 ? ((const float*)p)[idx] : bf2f(((const u16*)p)[idx]);
}

// detect helper: one wave scans first 512 u16 words of x; >50 insane => fp32
static __device__ __forceinline__ int detect_wave(const u16* xw, int lane)
{
    int insane = 0;
    for (int k = lane; k < 512; k += 64) {
        u16 w = xw[k];
        int ex = (w >> 7) & 0xFF;
        bool sane = ((w & 0x7FFF) == 0) || (ex >= 96 && ex <= 159);
        insane += sane ? 0 : 1;
    }
    for (int off = 32; off; off >>= 1) insane += __shfl_down(insane, off);
    return insane;   // valid in lane 0
}

// --------------------------------------------------------------------------
// k_cvt: canonicalize x -> bf16 xb  (detect fused; block 0 publishes flag)
// --------------------------------------------------------------------------
__global__ __launch_bounds__(256) void k_cvt(const void* __restrict__ xin,
                                             u16* __restrict__ xb, int* __restrict__ flag)
{
    __shared__ int sflag;
    int t = threadIdx.x;
    if (t < 64) {
        int insane = detect_wave((const u16*)xin, t);
        if (t == 0) {
            sflag = (insane > 50) ? 1 : 0;
            if (blockIdx.x == 0) *flag = sflag;
        }
    }
    __syncthreads();
    int isf32 = sflag;
    int i = blockIdx.x * 256 + t;
    if (i >= NN * 8) return;
    if (isf32) {
        const float* xf = (const float*)xin;
        u16 o[8];
#pragma unroll
        for (int j = 0; j < 8; ++j) o[j] = f2bf(xf[i * 8 + j]);
        uint4 v;
        v.x = (u32)o[0] | ((u32)o[1] << 16);
        v.y = (u32)o[2] | ((u32)o[3] << 16);
        v.z = (u32)o[4] | ((u32)o[5] << 16);
        v.w = (u32)o[6] | ((u32)o[7] << 16);
        ((uint4*)xb)[i] = v;
    } else {
        ((uint4*)xb)[i] = ((const uint4*)xin)[i];
    }
}

// --------------------------------------------------------------------------
// K0: swizzled B operand per relation in MFMA B-frag order (detect fused)
// --------------------------------------------------------------------------
__global__ __launch_bounds__(256) void k0_prep(const void* __restrict__ xin,
                        const void* __restrict__ cw, const void* __restrict__ al,
                        const void* __restrict__ ar, u16* __restrict__ Bpre)
{
    __shared__ int sflag;
    int t = threadIdx.x;
    if (t < 64) {
        int insane = detect_wave((const u16*)xin, t);
        if (t == 0) sflag = (insane > 50) ? 1 : 0;
    }
    __syncthreads();
    int isf32 = sflag;
    int tid = blockIdx.x * 256 + t;
    if (tid >= NR * 5120) return;
    int r = tid / 5120, rem = tid % 5120;
    int c = rem >> 3, j = rem & 7;
    int nt = c >> 7, kk = (c >> 6) & 1, lc = c & 63;
    int i = kk * 32 + ((lc >> 4) << 3) + j;
    int d = lc & 15;
    u16 val;
    if (nt < 4) {
        val = f2bf(ldf(cw, ((r * 4 + nt) * 64 + i) * 16 + d, isf32));
    } else if (d < 8) {
        int h = d >> 1;
        const void* attn = (d & 1) ? ar : al;
        float s = 0.f;
        for (int dd = 0; dd < 16; ++dd)
            s += ldf(cw, ((r * 4 + h) * 64 + i) * 16 + dd, isf32)
               * ldf(attn, (r * 4 + h) * 16 + dd, isf32);
        val = f2bf(s);
    } else {
        val = 0;
    }
    Bpre[tid] = val;
}

// --------------------------------------------------------------------------
// K1 v2: block = 64 nodes, loops over all 8 relations in-block.
// A staged once; per rel: stage B, MFMA, el/er write, feat via ldsF.
// --------------------------------------------------------------------------
__global__ __launch_bounds__(256) void k1_feat(
    const u16* __restrict__ xb, const u16* __restrict__ Bpre,
    u16* __restrict__ feat_all, float* __restrict__ el_all, float* __restrict__ er_all)
{
    __shared__ alignas(16) u16 ldsA[4096];
    __shared__ alignas(16) u16 ldsB[5120];
    __shared__ alignas(16) u16 ldsF[4096];
    int n0 = blockIdx.x * 64;
    int tid = threadIdx.x;
    int wave = tid >> 6, lane = tid & 63;
    int col = lane & 15, quad = lane >> 4;

    // stage A swizzled (once)
    for (int c = tid; c < 512; c += 256) {
        int mt = c >> 7, kk = (c >> 6) & 1, lc = c & 63;
        int node = n0 + mt * 16 + (lc & 15);
        if (node >= NN) node = NN - 1;
        int kbase = kk * 32 + ((lc >> 4) << 3);
        *(uint4*)&ldsA[c * 8] = *(const uint4*)&xb[node * 64 + kbase];
    }
    __syncthreads();
    bf16x8 afrag0 = *(bf16x8*)&ldsA[((wave * 2 + 0) * 64 + lane) * 8];
    bf16x8 afrag1 = *(bf16x8*)&ldsA[((wave * 2 + 1) * 64 + lane) * 8];

    for (int r = 0; r < NR; ++r) {
        for (int c = tid; c < 640; c += 256)
            *(uint4*)&ldsB[c * 8] = *(const uint4*)&Bpre[r * 5120 + c * 8];
        __syncthreads();   // B staged; prev iter's ldsF fully consumed

        f32x4 acc[5];
#pragma unroll
        for (int nt = 0; nt < 5; ++nt) acc[nt] = f32x4{0.f, 0.f, 0.f, 0.f};
#pragma unroll
        for (int nt = 0; nt < 5; ++nt) {
            bf16x8 b0 = *(bf16x8*)&ldsB[((nt * 2 + 0) * 64 + lane) * 8];
            bf16x8 b1 = *(bf16x8*)&ldsB[((nt * 2 + 1) * 64 + lane) * 8];
            acc[nt] = __builtin_amdgcn_mfma_f32_16x16x32_bf16(afrag0, b0, acc[nt], 0, 0, 0);
            acc[nt] = __builtin_amdgcn_mfma_f32_16x16x32_bf16(afrag1, b1, acc[nt], 0, 0, 0);
        }

        if (col < 8) {
            int h = col >> 1;
            float* dstp = (col & 1) ? er_all : el_all;
#pragma unroll
            for (int reg = 0; reg < 4; ++reg) {
                int node = n0 + wave * 16 + quad * 4 + reg;
                if (node < NN) dstp[(r * NN + node) * 4 + h] = acc[4][reg];
            }
        }
#pragma unroll
        for (int nt = 0; nt < 4; ++nt) {
            int cg = nt * 16 + col;
#pragma unroll
            for (int reg = 0; reg < 4; ++reg) {
                int row = quad * 4 + reg;
                ldsF[(wave * 16 + row) * 64 + cg] = f2bf(acc[nt][reg]);
            }
        }
        __syncthreads();   // ldsF complete; all B reads done (safe to restage)
        for (int c = tid; c < 512; c += 256) {
            int nl = c >> 3, part = c & 7;
            int node = n0 + nl;
            if (node < NN)
                *(uint4*)&feat_all[(r * NN + node) * 64 + part * 8] = *(uint4*)&ldsF[c * 8];
        }
    }
}

// --------------------------------------------------------------------------
// Binned counting sort by dst — no global atomics, coalesced writes.
// --------------------------------------------------------------------------
__global__ __launch_bounds__(256) void k_binA(const int* __restrict__ dsti,
                                              int* __restrict__ histT)
{
    __shared__ int hist[NBUCK];
    int t = threadIdx.x, blk = blockIdx.x;
    if (t < NBUCK) hist[t] = 0;
    __syncthreads();
    int base = blk * EB;
    for (int j = 0; j < EB; j += 256) {
        int e = base + j + t;
        if (e < NE) atomicAdd(&hist[dsti[e] >> 9], 1);
    }
    __syncthreads();
    if (t < NBUCK) histT[t * NBLK + blk] = hist[t];
}

__global__ __launch_bounds__(256) void k_scanB1(int* __restrict__ histT,
                                                int* __restrict__ bsum)
{
    __shared__ int wtot[4];
    int t = threadIdx.x;
    int gi = blockIdx.x * 256 + t;
    int v = (gi < NT) ? histT[gi] : 0;
    int lane = t & 63, w = t >> 6;
    int s = v;
#pragma unroll
    for (int m = 1; m < 64; m <<= 1) {
        int u = __shfl_up(s, m);
        if (lane >= m) s += u;
    }
    if (lane == 63) wtot[w] = s;
    __syncthreads();
    int wb = 0;
    for (int i = 0; i < w; ++i) wb += wtot[i];
    if (gi < NT) histT[gi] = wb + s - v;
    if (t == 255) bsum[blockIdx.x] = wb + s;
}

__global__ __launch_bounds__(1024) void k_scanB2(const int* __restrict__ bsum,
                                                 int* __restrict__ boff)
{
    __shared__ int wtot[16];
    int t = threadIdx.x;
    int v = (t < NBB) ? bsum[t] : 0;
    int lane = t & 63, w = t >> 6;
    int s = v;
#pragma unroll
    for (int m = 1; m < 64; m <<= 1) {
        int u = __shfl_up(s, m);
        if (lane >= m) s += u;
    }
    if (lane == 63) wtot[w] = s;
    __syncthreads();
    int wb = 0;
    for (int i = 0; i < w; ++i) wb += wtot[i];
    if (t < NBB) boff[t] = wb + s - v;
}

__global__ __launch_bounds__(256) void k_scanB3(const int* __restrict__ boff,
                                                int* __restrict__ histT,
                                                int* __restrict__ bstart)
{
    int gi = blockIdx.x * 256 + threadIdx.x;
    if (gi < NT) {
        int val = histT[gi] + boff[blockIdx.x];
        histT[gi] = val;
        if (gi % NBLK == 0) bstart[gi / NBLK] = val;
    }
    if (gi == 0) bstart[NBUCK] = NE;
}

// key = (dst&511)<<20 | rel<<17 | src   (29 bits)
__global__ __launch_bounds__(256) void k_binC(
    const int* __restrict__ srci, const int* __restrict__ dsti,
    const int* __restrict__ reli, const int* __restrict__ histT,
    int* __restrict__ key_b)
{
    __shared__ int cur[NBUCK];
    int t = threadIdx.x, blk = blockIdx.x;
    if (t < NBUCK) cur[t] = histT[t * NBLK + blk];
    __syncthreads();
    int base = blk * EB;
    for (int j = 0; j < EB; j += 256) {
        int e = base + j + t;
        if (e < NE) {
            int d = dsti[e];
            int key = ((d & 511) << 20) | (reli[e] << 17) | srci[e];
            int pos = atomicAdd(&cur[d >> 9], 1);
            key_b[pos] = key;
        }
    }
}

__global__ __launch_bounds__(1024) void k_binD(
    const int* __restrict__ bstart, const int* __restrict__ key_b,
    int* __restrict__ key_s, int* __restrict__ off)
{
    __shared__ int cnt[512];
    __shared__ int wtot[8];
    int t = threadIdx.x, b = blockIdx.x;
    int s0 = bstart[b], s1 = bstart[b + 1];
    if (t < 512) cnt[t] = 0;
    __syncthreads();
    for (int j = s0 + t; j < s1; j += 1024)
        atomicAdd(&cnt[(key_b[j] >> 20) & 511], 1);
    __syncthreads();
    int excl = 0;
    if (t < 512) {
        int v = cnt[t];
        int lane = t & 63, w = t >> 6;
        int s = v;
#pragma unroll
        for (int m = 1; m < 64; m <<= 1) {
            int u = __shfl_up(s, m);
            if (lane >= m) s += u;
        }
        if (lane == 63) wtot[w] = s;
        __syncthreads();
        int wb = 0;
        for (int i = 0; i < w; ++i) wb += wtot[i];
        excl = s0 + wb + s - v;
        int d = (b << 9) + t;
        if (d < NN) off[d] = excl;
    } else {
        __syncthreads();
    }
    __syncthreads();
    if (t < 512) cnt[t] = excl;
    if (b == 0 && t == 0) off[NN] = NE;
    __syncthreads();
    for (int j = s0 + t; j < s1; j += 1024) {
        int key = key_b[j];
        int pos = atomicAdd(&cnt[(key >> 20) & 511], 1);
        key_s[pos] = key;
    }
}

// --------------------------------------------------------------------------
// K3 v4: block = 64 consecutive dsts, wave = 16 contiguous dsts. Lean LDS
// (18.2KB -> 8 blocks/CU). Stage wave's edge run (coalesced keys, el + er
// gathers (er L1-hot: 512 lines/block), exp) -> LDS key+ee. Inner loop:
// eg/fl layout, 4 independent 8B feat loads in flight, free denominator,
// 10-shuffle reduce, 8B store.
// --------------------------------------------------------------------------
__global__ __launch_bounds__(256) void k3_node(
    const int* __restrict__ off, const int* __restrict__ key_s,
    const float* __restrict__ el_all, const float* __restrict__ er_all,
    const u16* __restrict__ feat_all, const void* __restrict__ bias,
    const int* __restrict__ flag, void* __restrict__ out)
{
    __shared__ int   ldsOffs[65];
    __shared__ int   ldsKey[4][CAP];     // 3.5KB
    __shared__ float ldsEE[4][CAP][4];   // 14.3KB
    int t = threadIdx.x;
    int wave = t >> 6, lane = t & 63;
    int eg = lane >> 4;          // edge subclass 0..3
    int fl = lane & 15;          // feature quad
    int h  = fl >> 2;            // head
    int d0 = blockIdx.x * 64;
    int isf32 = *flag;

    if (t < 65) ldsOffs[t] = off[min(d0 + t, NN)];
    __syncthreads();

    int dlo = wave * 16;
    int estart = ldsOffs[dlo], eend = ldsOffs[dlo + 16];
    int count = eend - estart;
    int scount = min(count, CAP);

    // stage this wave's edges
    for (int j = lane; j < scount; j += 64) {
        int key = key_s[estart + j];
        int rel = (key >> 17) & 7, src = key & 131071;
        int d = d0 + ((key >> 20) & 63);     // d0 is 64-aligned
        int kk = rel * NN + src;
        f32x4 el = *(const f32x4*)&el_all[kk * 4];
        f32x4 er = *(const f32x4*)&er_all[(rel * NN + d) * 4];
        f32x4 ee;
#pragma unroll
        for (int q = 0; q < 4; ++q) {
            float v = el[q] + er[q];
            v = v > 0.f ? v : 0.2f * v;
            ee[q] = __expf(v);
        }
        ldsKey[wave][j] = kk;
        *(f32x4*)&ldsEE[wave][j][0] = ee;
    }
    // same-wave LDS write->read ordered via lgkmcnt

    float bv0 = ldf(bias, fl * 4 + 0, isf32);
    float bv1 = ldf(bias, fl * 4 + 1, isf32);
    float bv2 = ldf(bias, fl * 4 + 2, isf32);
    float bv3 = ldf(bias, fl * 4 + 3, isf32);

    for (int nl = 0; nl < 16; ++nl) {
        int d = d0 + dlo + nl;
        if (d >= NN) break;
        int s  = ldsOffs[dlo + nl] - estart;
        int e1 = ldsOffs[dlo + nl + 1] - estart;
        float acc0 = 0.f, acc1 = 0.f, acc2 = 0.f, acc3 = 0.f, accW = 0.f;

        int e1c = min(e1, CAP);
        for (int base = s; base < e1c; base += 16) {
            int kk[4]; float w[4];
#pragma unroll
            for (int q = 0; q < 4; ++q) {
                int idx = base + q * 4 + eg;
                bool vld = idx < e1c;
                kk[q] = vld ? ldsKey[wave][idx] : 0;
                w[q]  = vld ? ldsEE[wave][idx][h] : 0.f;
            }
            uint2 u[4];
#pragma unroll
            for (int q = 0; q < 4; ++q)
                u[q] = *(const uint2*)&feat_all[kk[q] * 64 + fl * 4];
#pragma unroll
            for (int q = 0; q < 4; ++q) {
                acc0 += bflo(u[q].x) * w[q];
                acc1 += bfhi(u[q].x) * w[q];
                acc2 += bflo(u[q].y) * w[q];
                acc3 += bfhi(u[q].y) * w[q];
                accW += w[q];
            }
        }
        // overflow path (statistically never; correctness fallback)
        for (int base = max(s, CAP); base < e1; base += 4) {
            int idx = base + eg;
            int kk0 = 0; float w0 = 0.f;
            if (idx < e1) {
                int key = key_s[estart + idx];
                int rel = (key >> 17) & 7, src = key & 131071;
                kk0 = rel * NN + src;
                float v = el_all[kk0 * 4 + h] + er_all[(rel * NN + d) * 4 + h];
                v = v > 0.f ? v : 0.2f * v;
                w0 = __expf(v);
            }
            uint2 u = *(const uint2*)&feat_all[kk0 * 64 + fl * 4];
            acc0 += bflo(u.x) * w0;
            acc1 += bfhi(u.x) * w0;
            acc2 += bflo(u.y) * w0;
            acc3 += bfhi(u.y) * w0;
            accW += w0;
        }

#pragma unroll
        for (int m = 16; m < 64; m <<= 1) {
            acc0 += __shfl_xor(acc0, m);
            acc1 += __shfl_xor(acc1, m);
            acc2 += __shfl_xor(acc2, m);
            acc3 += __shfl_xor(acc3, m);
            accW += __shfl_xor(accW, m);
        }
        float invh = 1.f / fmaxf(accW, 1e-16f);
        if (eg == 0) {
            float o0 = acc0 * invh + bv0;
            float o1 = acc1 * invh + bv1;
            float o2 = acc2 * invh + bv2;
            float o3 = acc3 * invh + bv3;
            if (isf32) {
                ((f32x4*)out)[d * 16 + fl] = f32x4{o0, o1, o2, o3};
            } else {
                uint2 st;
                st.x = (u32)f2bf(o0) | ((u32)f2bf(o1) << 16);
                st.y = (u32)f2bf(o2) | ((u32)f2bf(o3) << 16);
                *(uint2*)&((u16*)out)[d * 64 + fl * 4] = st;
            }
        }
    }
}

extern "C" void kernel_launch(void* const* d_in, const int* in_sizes, int n_in,
                              void* d_out, int out_size, void* d_ws, size_t ws_size,
                              hipStream_t stream)
{
    const void* x   = d_in[0];
    const int* srci = (const int*)d_in[1];
    const int* dsti = (const int*)d_in[2];
    const int* reli = (const int*)d_in[3];
    const void* cw  = d_in[4];
    const void* al  = d_in[5];
    const void* ar  = d_in[6];
    const void* hb  = d_in[7];

    // workspace layout (bytes, 16B-aligned), ~150.1 MB total
    char* ws = (char*)d_ws;
    u16*   feat_all = (u16*)  (ws + 0);            // 102,400,000
    float* el_all   = (float*)(ws + 102400000);    //  12,800,000
    float* er_all   = (float*)(ws + 115200000);    //  12,800,000
    int*   key_s    = (int*)  (ws + 128000000);    //   4,000,000
    int*   key_b    = (int*)  (ws + 132000000);    //   4,000,000
    int*   off      = (int*)  (ws + 136000000);    //     400,064
    int*   histT    = (int*)  (ws + 136400064);    //     765,968
    int*   bsum     = (int*)  (ws + 137166032);    //       3,008
    int*   boff     = (int*)  (ws + 137169040);    //       3,008
    int*   bstart   = (int*)  (ws + 137172048);    //         832
    u16*   Bpre     = (u16*)  (ws + 137172880);    //      81,920
    u16*   xb       = (u16*)  (ws + 137254800);    //  12,800,000
    int*   flag     = (int*)  (ws + 150054800);    //           4

    k_cvt<<<(NN * 8 + 255) / 256, 256, 0, stream>>>(x, xb, flag);
    k0_prep<<<(NR * 5120 + 255) / 256, 256, 0, stream>>>(x, cw, al, ar, Bpre);
    k1_feat<<<(NN + 63) / 64, 256, 0, stream>>>(xb, Bpre, feat_all, el_all, er_all);
    k_binA<<<NBLK, 256, 0, stream>>>(dsti, histT);
    k_scanB1<<<NBB, 256, 0, stream>>>(histT, bsum);
    k_scanB2<<<1, 1024, 0, stream>>>(bsum, boff);
    k_scanB3<<<NBB, 256, 0, stream>>>(boff, histT, bstart);
    k_binC<<<NBLK, 256, 0, stream>>>(srci, dsti, reli, histT, key_b);
    k_binD<<<NBUCK, 1024, 0, stream>>>(bstart, key_b, key_s, off);
    k3_node<<<(NN + 63) / 64, 256, 0, stream>>>(off, key_s, el_all, er_all, feat_all,
                                                hb, flag, d_out);
}